// Round 1
// baseline (402.033 us; speedup 1.0000x reference)
//
#include <hip/hip_runtime.h>
#include <hip/hip_bf16.h>
#include <cstdint>

// GRU: B=2048, T=256, F=64, H=32. All inputs fp32. Output fp32 [2048].
// Phase 1: xg[b,t,g] = x[b,t,:]·W_ih[g,:] + b_ih[g]   (stored bf16 in d_ws, 96 MB)
// Phase 2: sequential scan over T per batch; thread=(b,h); W_hh in VGPRs;
//          h broadcast via intra-wave shuffles; head fused as epilogue.

#define BATCH 2048
#define TSEQ  256
#define FDIM  64
#define G3    96
#define BT    (BATCH * TSEQ)   // 524288 rows

// ---------------- Phase 1: projection GEMM (fp32 compute, bf16 out) ----------
// grid BT/128 blocks x 256 threads. Block tile: 128 rows x 96 cols.
// thread (rt=tid&31, gt=tid>>5): C-tile 4 rows (strided 32) x 12 cols.
__global__ __launch_bounds__(256, 2)
void proj_kernel(const float* __restrict__ x, const float* __restrict__ W_ih,
                 const float* __restrict__ b_ih, __hip_bfloat16* __restrict__ xg)
{
    __shared__ float xt[64][129];   // [k][row], padded: conflict-free row reads
    __shared__ float ws[96 * 65];   // [g][k], padded

    const int tid = threadIdx.x;
    const int rt  = tid & 31;
    const int gt  = tid >> 5;                 // 0..7, 12 cols each
    const long row0 = (long)blockIdx.x * 128;

    // stage x tile (128 rows x 64 cols) -> transposed LDS
    const float4* x4 = (const float4*)(x + row0 * FDIM);
    #pragma unroll
    for (int it = 0; it < 8; ++it) {
        int idx = it * 256 + tid;             // float4 index within tile
        float4 v = x4[idx];
        int e = idx * 4;
        int r = e >> 6;
        int c = e & 63;
        xt[c + 0][r] = v.x; xt[c + 1][r] = v.y;
        xt[c + 2][r] = v.z; xt[c + 3][r] = v.w;
    }
    // stage W_ih (96 x 64)
    const float4* w4 = (const float4*)W_ih;
    #pragma unroll
    for (int it = 0; it < 6; ++it) {
        int idx = it * 256 + tid;
        float4 v = w4[idx];
        int e = idx * 4;
        int g = e >> 6;
        int k = e & 63;
        float* wrow = ws + g * 65 + k;
        wrow[0] = v.x; wrow[1] = v.y; wrow[2] = v.z; wrow[3] = v.w;
    }

    float bias[12];
    #pragma unroll
    for (int j = 0; j < 12; ++j) bias[j] = b_ih[gt * 12 + j];

    __syncthreads();

    float acc[4][12];
    #pragma unroll
    for (int i = 0; i < 4; ++i)
        #pragma unroll
        for (int j = 0; j < 12; ++j) acc[i][j] = 0.f;

    #pragma unroll 4
    for (int k = 0; k < 64; ++k) {
        float xv0 = xt[k][rt];
        float xv1 = xt[k][rt + 32];
        float xv2 = xt[k][rt + 64];
        float xv3 = xt[k][rt + 96];
        #pragma unroll
        for (int j = 0; j < 12; ++j) {
            float w = ws[(gt * 12 + j) * 65 + k];   // 2 addrs/wave: broadcast
            acc[0][j] += xv0 * w;
            acc[1][j] += xv1 * w;
            acc[2][j] += xv2 * w;
            acc[3][j] += xv3 * w;
        }
    }

    #pragma unroll
    for (int i = 0; i < 4; ++i) {
        long r = row0 + rt + 32 * i;
        __hip_bfloat16* dst = xg + r * G3 + gt * 12;
        #pragma unroll
        for (int j = 0; j < 12; ++j)
            dst[j] = __float2bfloat16(acc[i][j] + bias[j]);
    }
}

// ---------------- Phase 2: recurrence + head --------------------------------
// grid 256 blocks x 256 threads; block owns 8 batches; thread=(b_local, h).
// Each batch's 32 h-threads occupy one half-wave -> shuffle broadcast, no LDS.
__global__ __launch_bounds__(256, 1)
void gru_kernel(const __hip_bfloat16* __restrict__ xg,
                const float* __restrict__ W_hh, const float* __restrict__ b_hh,
                const float* __restrict__ W_head, const float* __restrict__ b_head,
                float* __restrict__ out)
{
    const int tid = threadIdx.x;
    const int h   = tid & 31;
    const int bl  = tid >> 5;                 // 0..7
    const long b  = (long)blockIdx.x * 8 + bl;

    // W_hh rows for this hidden unit: r,z,n — kept in VGPRs (96 regs)
    float wr[32], wz[32], wn[32];
    #pragma unroll
    for (int k = 0; k < 32; ++k) {
        wr[k] = W_hh[(h     ) * 32 + k];
        wz[k] = W_hh[(32 + h) * 32 + k];
        wn[k] = W_hh[(64 + h) * 32 + k];
    }
    const float bhr = b_hh[h], bhz = b_hh[32 + h], bhn = b_hh[64 + h];

    const __hip_bfloat16* xp = xg + b * (long)TSEQ * G3;
    const int base = tid & 32;                // half-wave base for shuffles
    float h_own = 0.f;

    // software-pipelined xg loads (one step ahead)
    float xr = __bfloat162float(xp[h]);
    float xz = __bfloat162float(xp[32 + h]);
    float xn = __bfloat162float(xp[64 + h]);

    for (int t = 0; t < TSEQ; ++t) {
        float nxr = 0.f, nxz = 0.f, nxn = 0.f;
        if (t + 1 < TSEQ) {
            const __hip_bfloat16* q = xp + (t + 1) * G3;
            nxr = __bfloat162float(q[h]);
            nxz = __bfloat162float(q[32 + h]);
            nxn = __bfloat162float(q[64 + h]);
        }
        // broadcast h vector of this batch from its 32 lanes
        float hv[32];
        #pragma unroll
        for (int k = 0; k < 32; ++k) hv[k] = __shfl(h_own, base + k, 64);

        float hr = bhr, hz = bhz, hn = bhn;
        #pragma unroll
        for (int k = 0; k < 32; ++k) {
            hr += wr[k] * hv[k];
            hz += wz[k] * hv[k];
            hn += wn[k] * hv[k];
        }
        float r = 1.f / (1.f + __expf(-(xr + hr)));
        float z = 1.f / (1.f + __expf(-(xz + hz)));
        float a = xn + r * hn;
        float e = __expf(-2.f * fabsf(a));
        float th = copysignf((1.f - e) / (1.f + e), a);
        h_own = (1.f - z) * th + z * h_own;

        xr = nxr; xz = nxz; xn = nxn;
    }

    // head: y[b] = sigmoid(h · W_head + b_head); reduce within half-wave
    float v = h_own * W_head[h];
    #pragma unroll
    for (int m = 16; m >= 1; m >>= 1) v += __shfl_xor(v, m, 64);
    if (h == 0) out[b] = 1.f / (1.f + __expf(-(v + b_head[0])));
}

extern "C" void kernel_launch(void* const* d_in, const int* in_sizes, int n_in,
                              void* d_out, int out_size, void* d_ws, size_t ws_size,
                              hipStream_t stream)
{
    const float* x      = (const float*)d_in[0];
    const float* W_ih   = (const float*)d_in[1];
    const float* W_hh   = (const float*)d_in[2];
    const float* b_ih   = (const float*)d_in[3];
    const float* b_hh   = (const float*)d_in[4];
    const float* W_head = (const float*)d_in[5];
    const float* b_head = (const float*)d_in[6];
    float* out = (float*)d_out;

    // workspace: xg bf16, BT*96*2 = 96 MB
    __hip_bfloat16* xg = (__hip_bfloat16*)d_ws;

    proj_kernel<<<BT / 128, 256, 0, stream>>>(x, W_ih, b_ih, xg);
    gru_kernel<<<BATCH / 8, 256, 0, stream>>>(xg, W_hh, b_hh, W_head, b_head, out);
}